// Round 3
// baseline (768.303 us; speedup 1.0000x reference)
//
#include <hip/hip_runtime.h>
#include <cmath>

#define NUM_LEVELS 16
#define TABLE_SIZE 524288
#define TMASK (TABLE_SIZE - 1)
#define HASH_PRIME 2654435761u
#define T_SAMPLES 192
#define BLOCK 256

typedef __bf16 bf16x8 __attribute__((ext_vector_type(8)));
typedef float f32x4 __attribute__((ext_vector_type(4)));

struct LvlParams {
    float s[NUM_LEVELS];
    int   res[NUM_LEVELS];
    int   hashed[NUM_LEVELS];
};

__device__ __forceinline__ float softplus10(float x) {
    float t = 10.0f * x;
    float e = __expf(-fabsf(t));
    return (fmaxf(t, 0.0f) + __logf(1.0f + e)) * 0.1f;
}

typedef __attribute__((address_space(1))) const void CGV;
typedef __attribute__((address_space(3))) void LDSV;

__device__ __forceinline__ void dma_gather16(const void* gaddr, void* lds_wave_base) {
    // per-lane global address; LDS dest = wave-uniform base + lane*16 (m104 semantics)
    __builtin_amdgcn_global_load_lds((CGV*)gaddr, (LDSV*)lds_wave_base, 16, 0, 0);
}

__device__ __forceinline__ void corner_idx(int cx, int cy, int res, int hashed,
                                           int& i00, int& i01, int& i10, int& i11) {
    if (hashed) {
        unsigned hy0 = (unsigned)cy * HASH_PRIME;
        unsigned hy1 = (unsigned)(cy + 1) * HASH_PRIME;
        i00 = (int)(((unsigned)cx ^ hy0) & TMASK);
        i01 = (int)(((unsigned)cx ^ hy1) & TMASK);
        i10 = (int)(((unsigned)(cx + 1) ^ hy0) & TMASK);
        i11 = (int)(((unsigned)(cx + 1) ^ hy1) & TMASK);
    } else {
        i00 = cy * res + cx; i10 = i00 + 1;
        i01 = i00 + res;     i11 = i01 + 1;
    }
}

// ---- prep: pack W0 (f32 [k][n] row-major) into MFMA-B-fragment order bf16 ----
// flat f: j=f&7 (frag elem), lx=(f>>3)&15, q=(f>>7)&3, nt=(f>>9)&3, kc=f>>11
// k = kc*32+q*8+j ; n = nt*16+lx.  Main kernel lane (lx,q) loads one bf16x8 at
// slot ((kc*4+nt)*64 + q*16 + lx) -> fully coalesced 1KB per instruction.
__global__ void pack_w0(const float* __restrict__ W0, __bf16* __restrict__ w0f) {
    const int t = threadIdx.x;
    #pragma unroll
    for (int i = 0; i < 16; ++i) {
        int f = t * 16 + i;
        int j = f & 7, lx = (f >> 3) & 15, q = (f >> 7) & 3, nt = (f >> 9) & 3, kc = f >> 11;
        int k = kc * 32 + q * 8 + j;
        int n = nt * 16 + lx;
        w0f[f] = (__bf16)W0[k * 64 + n];
    }
}

__launch_bounds__(BLOCK, 5)
__global__ void nerf_fused(const float* __restrict__ x,
                           const float* __restrict__ emb,
                           const __bf16* __restrict__ w0f,
                           const float* __restrict__ b0,
                           const float* __restrict__ W1,
                           const float* __restrict__ b1,
                           float* __restrict__ out,
                           LvlParams lp) {
    // Single 32 KB LDS region, used twice:
    //  (a) DMA landing zone for levels 14,15: 2lvl x 4corner x 4wave x 64lane x 16B = 32768 B
    //  (b) bf16 feats tile [256][64] (32768 B), XOR-swizzled 16B chunks.
    // 32 KB/block -> 5 blocks/CU (160 KB pool), 20 waves/CU.
    __shared__ __align__(16) char uSh[BLOCK * 64 * 2];

    const int tid  = threadIdx.x;
    const int lane = tid & 63, wave = tid >> 6;

    // ---- ray setup ----
    const int gp  = blockIdx.x * BLOCK + tid;
    const int ray = gp / T_SAMPLES;
    const int t   = gp - ray * T_SAMPLES;

    const float2 o  = *(const float2*)(x + (size_t)ray * (T_SAMPLES * 2));
    const float2 ep = *(const float2*)(x + (size_t)ray * (T_SAMPLES * 2) + (T_SAMPLES - 1) * 2);
    float rdx = ep.x - o.x, rdy = ep.y - o.y;
    float inv = 1.0f / sqrtf(rdx * rdx + rdy * rdy);
    rdx *= inv; rdy *= inv;
    const float z = (float)((double)t * (2.0 / 191.0));
    float px = fminf(fmaxf(o.x + rdx * z, -1.0f), 1.0f);
    float py = fminf(fmaxf(o.y + rdy * z, -1.0f), 1.0f);
    const float ux = (px + 1.0f) * 0.5f;
    const float uy = (py + 1.0f) * 0.5f;

    f32x4* land = (f32x4*)uSh;   // slot = ((lvl*4+c)*4 + wave)*64 + lane

    // ---- issue DMA gathers for levels 14,15 (no VGPR held, in flight now) --
    float frx[2], fry[2];
    #pragma unroll
    for (int li = 0; li < 2; ++li) {
        const int l = 14 + li;
        float posx = ux * lp.s[l] + 0.5f, posy = uy * lp.s[l] + 0.5f;
        float pfx = floorf(posx), pfy = floorf(posy);
        frx[li] = posx - pfx; fry[li] = posy - pfy;
        int cx = (int)pfx, cy = (int)pfy;
        int i00, i01, i10, i11;
        corner_idx(cx, cy, lp.res[l], lp.hashed[l], i00, i01, i10, i11);
        const f32x4* tb = (const f32x4*)(emb + (size_t)l * (TABLE_SIZE * 4));
        dma_gather16(tb + i00, land + ((li * 4 + 0) * 4 + wave) * 64);
        dma_gather16(tb + i01, land + ((li * 4 + 1) * 4 + wave) * 64);
        dma_gather16(tb + i10, land + ((li * 4 + 2) * 4 + wave) * 64);
        dma_gather16(tb + i11, land + ((li * 4 + 3) * 4 + wave) * 64);
    }

    // ---- issue register loads for levels 12,13 (held across 0-11) ----
    f32x4 cre[8]; float frx2[2], fry2[2];
    #pragma unroll
    for (int li = 0; li < 2; ++li) {
        const int l = 12 + li;
        float posx = ux * lp.s[l] + 0.5f, posy = uy * lp.s[l] + 0.5f;
        float pfx = floorf(posx), pfy = floorf(posy);
        frx2[li] = posx - pfx; fry2[li] = posy - pfy;
        int cx = (int)pfx, cy = (int)pfy;
        int i00, i01, i10, i11;
        corner_idx(cx, cy, lp.res[l], lp.hashed[l], i00, i01, i10, i11);
        const f32x4* tb = (const f32x4*)(emb + (size_t)l * (TABLE_SIZE * 4));
        cre[li * 4 + 0] = tb[i00];
        cre[li * 4 + 1] = tb[i01];
        cre[li * 4 + 2] = tb[i10];
        cre[li * 4 + 3] = tb[i11];
    }

    // ---- levels 0..11: small tables, L1/L2-hot, computed while DMAs fly ----
    bf16x8 stage[8];
    #pragma unroll
    for (int l = 0; l < 12; ++l) {
        float posx = ux * lp.s[l] + 0.5f, posy = uy * lp.s[l] + 0.5f;
        float pfx = floorf(posx), pfy = floorf(posy);
        float fx = posx - pfx, fy = posy - pfy;
        int cx = (int)pfx, cy = (int)pfy;
        int i00, i01, i10, i11;
        corner_idx(cx, cy, lp.res[l], lp.hashed[l], i00, i01, i10, i11);
        const f32x4* tb = (const f32x4*)(emb + (size_t)l * (TABLE_SIZE * 4));
        f32x4 c00 = tb[i00], c01 = tb[i01], c10 = tb[i10], c11 = tb[i11];
        float w00 = (1.0f - fx) * (1.0f - fy), w01 = (1.0f - fx) * fy;
        float w10 = fx * (1.0f - fy),          w11 = fx * fy;
        f32x4 a = c00 * w00 + c01 * w01 + c10 * w10 + c11 * w11;
        const int sj = l >> 1, so = (l & 1) * 4;
        stage[sj][so + 0] = (__bf16)a.x;
        stage[sj][so + 1] = (__bf16)a.y;
        stage[sj][so + 2] = (__bf16)a.z;
        stage[sj][so + 3] = (__bf16)a.w;
    }

    // ---- consume levels 12,13 from registers ----
    #pragma unroll
    for (int li = 0; li < 2; ++li) {
        const int l = 12 + li;
        float fx = frx2[li], fy = fry2[li];
        float w00 = (1.0f - fx) * (1.0f - fy), w01 = (1.0f - fx) * fy;
        float w10 = fx * (1.0f - fy),          w11 = fx * fy;
        f32x4 a = cre[li * 4 + 0] * w00 + cre[li * 4 + 1] * w01
                + cre[li * 4 + 2] * w10 + cre[li * 4 + 3] * w11;
        const int sj = l >> 1, so = (l & 1) * 4;
        stage[sj][so + 0] = (__bf16)a.x;
        stage[sj][so + 1] = (__bf16)a.y;
        stage[sj][so + 2] = (__bf16)a.z;
        stage[sj][so + 3] = (__bf16)a.w;
    }

    // ---- consume levels 14,15 from the LDS landing zone ----
    __builtin_amdgcn_s_waitcnt(0x0F70);   // vmcnt(0): DMA LDS writes visible
    #pragma unroll
    for (int li = 0; li < 2; ++li) {
        const int l = 14 + li;
        f32x4 c00 = land[((li * 4 + 0) * 4 + wave) * 64 + lane];
        f32x4 c01 = land[((li * 4 + 1) * 4 + wave) * 64 + lane];
        f32x4 c10 = land[((li * 4 + 2) * 4 + wave) * 64 + lane];
        f32x4 c11 = land[((li * 4 + 3) * 4 + wave) * 64 + lane];
        float fx = frx[li], fy = fry[li];
        float w00 = (1.0f - fx) * (1.0f - fy), w01 = (1.0f - fx) * fy;
        float w10 = fx * (1.0f - fy),          w11 = fx * fy;
        f32x4 a = c00 * w00 + c01 * w01 + c10 * w10 + c11 * w11;
        const int sj = l >> 1, so = (l & 1) * 4;
        stage[sj][so + 0] = (__bf16)a.x;
        stage[sj][so + 1] = (__bf16)a.y;
        stage[sj][so + 2] = (__bf16)a.z;
        stage[sj][so + 3] = (__bf16)a.w;
    }

    __syncthreads();   // everyone done reading the landing zone (aliases feS)

    // ---- write feats tile, XOR-swizzled 16B chunks: chunk j -> j^(row&7) ----
    __bf16 (*feS)[64] = (__bf16 (*)[64])uSh;
    {
        const int sw = tid & 7;
        #pragma unroll
        for (int j = 0; j < 8; ++j)
            *(bf16x8*)&feS[tid][(j ^ sw) * 8] = stage[j];
    }

    __syncthreads();

    // ---- phase 2: per-wave [64x64] @ [64x64] MFMA ----
    const int lx = lane & 15, q = lane >> 4;
    const int asw = lx & 7;                 // row&7 for a-frag rows

    f32x4 acc[4][4];
    #pragma unroll
    for (int mt = 0; mt < 4; ++mt)
        #pragma unroll
        for (int nt = 0; nt < 4; ++nt)
            acc[mt][nt] = (f32x4)(0.0f);

    #pragma unroll
    for (int kc = 0; kc < 2; ++kc) {
        bf16x8 afr[4];
        #pragma unroll
        for (int mt = 0; mt < 4; ++mt)
            afr[mt] = *(const bf16x8*)&feS[wave * 64 + mt * 16 + lx][((kc * 4 + q) ^ asw) * 8];
        #pragma unroll
        for (int nt = 0; nt < 4; ++nt) {
            // one coalesced b128 from the pre-packed, L1-hot W0 fragment buffer
            bf16x8 bfr = *(const bf16x8*)(w0f + (size_t)(((kc * 4 + nt) * 4 + q) * 16 + lx) * 8);
            #pragma unroll
            for (int mt = 0; mt < 4; ++mt)
                acc[mt][nt] = __builtin_amdgcn_mfma_f32_16x16x32_bf16(
                    afr[mt], bfr, acc[mt][nt], 0, 0, 0);
        }
    }

    // ---- epilogue: softplus10 -> dot W1 -> reduce over 16 col-lanes ----
    float b0v[4], w1v[4];
    #pragma unroll
    for (int nt = 0; nt < 4; ++nt) {
        b0v[nt] = b0[nt * 16 + lx];     // 16-lane broadcast, L1-hot
        w1v[nt] = W1[nt * 16 + lx];
    }
    const float b1v = b1[0];
    const float d0 = (float)(1.0 / 192.0);
    const float d1 = (float)(2.0 / 191.0);

    #pragma unroll
    for (int mt = 0; mt < 4; ++mt) {
        float part[4];
        #pragma unroll
        for (int r = 0; r < 4; ++r) {
            float p = 0.0f;
            #pragma unroll
            for (int nt = 0; nt < 4; ++nt)
                p += softplus10(acc[mt][nt][r] + b0v[nt]) * w1v[nt];
            p += __shfl_xor(p, 1, 64);
            p += __shfl_xor(p, 2, 64);
            p += __shfl_xor(p, 4, 64);
            p += __shfl_xor(p, 8, 64);
            part[r] = p;
        }
        if (lx == 0) {
            const int g0 = blockIdx.x * BLOCK + wave * 64 + mt * 16 + q * 4;
            const int tt = g0 % T_SAMPLES;           // multiple of 4, no wrap in vec4
            f32x4 ov;
            ov.x = softplus10(part[0] + b1v) * (tt == 0 ? d0 : d1);
            ov.y = softplus10(part[1] + b1v) * d1;
            ov.z = softplus10(part[2] + b1v) * d1;
            ov.w = softplus10(part[3] + b1v) * d1;
            *(f32x4*)(out + g0) = ov;
        }
    }
}

extern "C" void kernel_launch(void* const* d_in, const int* in_sizes, int n_in,
                              void* d_out, int out_size, void* d_ws, size_t ws_size,
                              hipStream_t stream) {
    const float* x   = (const float*)d_in[0];
    const float* emb = (const float*)d_in[1];
    const float* W0  = (const float*)d_in[2];
    const float* b0  = (const float*)d_in[3];
    const float* W1  = (const float*)d_in[4];
    const float* b1  = (const float*)d_in[5];
    float* out = (float*)d_out;
    __bf16* w0f = (__bf16*)d_ws;          // 4096 bf16 = 8 KB fragment buffer

    // Replicate numpy's level constants with the same double-precision libm ops.
    LvlParams lp;
    const double bb = std::exp((std::log(2048.0) - std::log(2.0)) / 15.0);
    for (int l = 0; l < NUM_LEVELS; ++l) {
        double sc = 2.0 * std::pow(bb, (double)l) - 1.0;
        int rr = (int)std::ceil(sc) + 1;
        lp.s[l] = (float)sc;
        lp.res[l] = rr;
        lp.hashed[l] = ((long long)rr * (long long)rr > (long long)TABLE_SIZE) ? 1 : 0;
    }

    pack_w0<<<1, 256, 0, stream>>>(W0, w0f);

    const int nblk = (out_size + BLOCK - 1) / BLOCK;   // 1572864/256 = 6144
    nerf_fused<<<nblk, BLOCK, 0, stream>>>(x, emb, w0f, b0, W1, b1, out, lp);
}

// Round 4
// 686.652 us; speedup vs baseline: 1.1189x; 1.1189x over previous
//
#include <hip/hip_runtime.h>
#include <cmath>

#define NUM_LEVELS 16
#define TABLE_SIZE 524288
#define TMASK (TABLE_SIZE - 1)
#define HASH_PRIME 2654435761u
#define T_SAMPLES 192
#define BLOCK 256

typedef __bf16 bf16x8 __attribute__((ext_vector_type(8)));
typedef float f32x4 __attribute__((ext_vector_type(4)));

struct LvlParams {
    float s[NUM_LEVELS];
    int   res[NUM_LEVELS];
    int   hashed[NUM_LEVELS];
};

__device__ __forceinline__ float softplus10(float x) {
    float t = 10.0f * x;
    float e = __expf(-fabsf(t));
    return (fmaxf(t, 0.0f) + __logf(1.0f + e)) * 0.1f;
}

typedef __attribute__((address_space(1))) const void CGV;
typedef __attribute__((address_space(3))) void LDSV;

__device__ __forceinline__ void dma_gather16(const void* gaddr, void* lds_wave_base) {
    // per-lane global address; LDS dest = wave-uniform base + lane*16 (m104 semantics)
    __builtin_amdgcn_global_load_lds((CGV*)gaddr, (LDSV*)lds_wave_base, 16, 0, 0);
}

__device__ __forceinline__ void corner_idx(int cx, int cy, int res, int hashed,
                                           int& i00, int& i01, int& i10, int& i11) {
    if (hashed) {
        unsigned hy0 = (unsigned)cy * HASH_PRIME;
        unsigned hy1 = (unsigned)(cy + 1) * HASH_PRIME;
        i00 = (int)(((unsigned)cx ^ hy0) & TMASK);
        i01 = (int)(((unsigned)cx ^ hy1) & TMASK);
        i10 = (int)(((unsigned)(cx + 1) ^ hy0) & TMASK);
        i11 = (int)(((unsigned)(cx + 1) ^ hy1) & TMASK);
    } else {
        i00 = cy * res + cx; i10 = i00 + 1;
        i01 = i00 + res;     i11 = i01 + 1;
    }
}

// ---- prep: pack W0 (f32 [k][n] row-major) into MFMA-B-fragment order bf16 ----
// flat f: j=f&7 (frag elem), lx=(f>>3)&15, q=(f>>7)&3, nt=(f>>9)&3, kc=f>>11
// k = kc*32+q*8+j ; n = nt*16+lx.  Main kernel lane (lx,q) loads one bf16x8 at
// slot ((kc*4+nt)*64 + q*16 + lx) -> fully coalesced 1KB per instruction.
__global__ void pack_w0(const float* __restrict__ W0, __bf16* __restrict__ w0f) {
    const int t = threadIdx.x;
    #pragma unroll
    for (int i = 0; i < 16; ++i) {
        int f = t * 16 + i;
        int j = f & 7, lx = (f >> 3) & 15, q = (f >> 7) & 3, nt = (f >> 9) & 3, kc = f >> 11;
        int k = kc * 32 + q * 8 + j;
        int n = nt * 16 + lx;
        w0f[f] = (__bf16)W0[k * 64 + n];
    }
}

// (256,4): reg budget 128/wave. Live peak is acc(64) + arch(~48) = ~112 -> no
// spill. (256,5) in round 3 forced a 96 cap -> acc spilled to scratch, +870 MB
// HBM traffic, dur 438->627. LDS 32 KB would allow 5 blocks; VGPR caps us at 4.
__launch_bounds__(BLOCK, 4)
__global__ void nerf_fused(const float* __restrict__ x,
                           const float* __restrict__ emb,
                           const __bf16* __restrict__ w0f,
                           const float* __restrict__ b0,
                           const float* __restrict__ W1,
                           const float* __restrict__ b1,
                           float* __restrict__ out,
                           LvlParams lp) {
    // Single 32 KB LDS region, used twice:
    //  (a) DMA landing zone for levels 14,15: 2lvl x 4corner x 4wave x 64lane x 16B
    //  (b) bf16 feats tile [256][64], XOR-swizzled 16B chunks (0 bank conflicts).
    __shared__ __align__(16) char uSh[BLOCK * 64 * 2];

    const int tid  = threadIdx.x;
    const int lane = tid & 63, wave = tid >> 6;

    // ---- ray setup ----
    const int gp  = blockIdx.x * BLOCK + tid;
    const int ray = gp / T_SAMPLES;
    const int t   = gp - ray * T_SAMPLES;

    const float2 o  = *(const float2*)(x + (size_t)ray * (T_SAMPLES * 2));
    const float2 ep = *(const float2*)(x + (size_t)ray * (T_SAMPLES * 2) + (T_SAMPLES - 1) * 2);
    float rdx = ep.x - o.x, rdy = ep.y - o.y;
    float inv = 1.0f / sqrtf(rdx * rdx + rdy * rdy);
    rdx *= inv; rdy *= inv;
    const float z = (float)((double)t * (2.0 / 191.0));
    float px = fminf(fmaxf(o.x + rdx * z, -1.0f), 1.0f);
    float py = fminf(fmaxf(o.y + rdy * z, -1.0f), 1.0f);
    const float ux = (px + 1.0f) * 0.5f;
    const float uy = (py + 1.0f) * 0.5f;

    f32x4* land = (f32x4*)uSh;   // slot = ((lvl*4+c)*4 + wave)*64 + lane

    // ---- issue DMA gathers for levels 14,15 (no VGPR held, in flight now) --
    float frx[2], fry[2];
    #pragma unroll
    for (int li = 0; li < 2; ++li) {
        const int l = 14 + li;
        float posx = ux * lp.s[l] + 0.5f, posy = uy * lp.s[l] + 0.5f;
        float pfx = floorf(posx), pfy = floorf(posy);
        frx[li] = posx - pfx; fry[li] = posy - pfy;
        int cx = (int)pfx, cy = (int)pfy;
        int i00, i01, i10, i11;
        corner_idx(cx, cy, lp.res[l], lp.hashed[l], i00, i01, i10, i11);
        const f32x4* tb = (const f32x4*)(emb + (size_t)l * (TABLE_SIZE * 4));
        dma_gather16(tb + i00, land + ((li * 4 + 0) * 4 + wave) * 64);
        dma_gather16(tb + i01, land + ((li * 4 + 1) * 4 + wave) * 64);
        dma_gather16(tb + i10, land + ((li * 4 + 2) * 4 + wave) * 64);
        dma_gather16(tb + i11, land + ((li * 4 + 3) * 4 + wave) * 64);
    }

    // ---- issue register loads for levels 12,13 (held across 0-11) ----
    f32x4 cre[8]; float frx2[2], fry2[2];
    #pragma unroll
    for (int li = 0; li < 2; ++li) {
        const int l = 12 + li;
        float posx = ux * lp.s[l] + 0.5f, posy = uy * lp.s[l] + 0.5f;
        float pfx = floorf(posx), pfy = floorf(posy);
        frx2[li] = posx - pfx; fry2[li] = posy - pfy;
        int cx = (int)pfx, cy = (int)pfy;
        int i00, i01, i10, i11;
        corner_idx(cx, cy, lp.res[l], lp.hashed[l], i00, i01, i10, i11);
        const f32x4* tb = (const f32x4*)(emb + (size_t)l * (TABLE_SIZE * 4));
        cre[li * 4 + 0] = tb[i00];
        cre[li * 4 + 1] = tb[i01];
        cre[li * 4 + 2] = tb[i10];
        cre[li * 4 + 3] = tb[i11];
    }

    // ---- levels 0..11: small tables, L1/L2-hot, computed while DMAs fly ----
    bf16x8 stage[8];
    #pragma unroll
    for (int l = 0; l < 12; ++l) {
        float posx = ux * lp.s[l] + 0.5f, posy = uy * lp.s[l] + 0.5f;
        float pfx = floorf(posx), pfy = floorf(posy);
        float fx = posx - pfx, fy = posy - pfy;
        int cx = (int)pfx, cy = (int)pfy;
        int i00, i01, i10, i11;
        corner_idx(cx, cy, lp.res[l], lp.hashed[l], i00, i01, i10, i11);
        const f32x4* tb = (const f32x4*)(emb + (size_t)l * (TABLE_SIZE * 4));
        f32x4 c00 = tb[i00], c01 = tb[i01], c10 = tb[i10], c11 = tb[i11];
        float w00 = (1.0f - fx) * (1.0f - fy), w01 = (1.0f - fx) * fy;
        float w10 = fx * (1.0f - fy),          w11 = fx * fy;
        f32x4 a = c00 * w00 + c01 * w01 + c10 * w10 + c11 * w11;
        const int sj = l >> 1, so = (l & 1) * 4;
        stage[sj][so + 0] = (__bf16)a.x;
        stage[sj][so + 1] = (__bf16)a.y;
        stage[sj][so + 2] = (__bf16)a.z;
        stage[sj][so + 3] = (__bf16)a.w;
    }

    // ---- consume levels 12,13 from registers ----
    #pragma unroll
    for (int li = 0; li < 2; ++li) {
        const int l = 12 + li;
        float fx = frx2[li], fy = fry2[li];
        float w00 = (1.0f - fx) * (1.0f - fy), w01 = (1.0f - fx) * fy;
        float w10 = fx * (1.0f - fy),          w11 = fx * fy;
        f32x4 a = cre[li * 4 + 0] * w00 + cre[li * 4 + 1] * w01
                + cre[li * 4 + 2] * w10 + cre[li * 4 + 3] * w11;
        const int sj = l >> 1, so = (l & 1) * 4;
        stage[sj][so + 0] = (__bf16)a.x;
        stage[sj][so + 1] = (__bf16)a.y;
        stage[sj][so + 2] = (__bf16)a.z;
        stage[sj][so + 3] = (__bf16)a.w;
    }

    // ---- consume levels 14,15 from the LDS landing zone ----
    __builtin_amdgcn_s_waitcnt(0x0F70);   // vmcnt(0): DMA LDS writes visible
    #pragma unroll
    for (int li = 0; li < 2; ++li) {
        const int l = 14 + li;
        f32x4 c00 = land[((li * 4 + 0) * 4 + wave) * 64 + lane];
        f32x4 c01 = land[((li * 4 + 1) * 4 + wave) * 64 + lane];
        f32x4 c10 = land[((li * 4 + 2) * 4 + wave) * 64 + lane];
        f32x4 c11 = land[((li * 4 + 3) * 4 + wave) * 64 + lane];
        float fx = frx[li], fy = fry[li];
        float w00 = (1.0f - fx) * (1.0f - fy), w01 = (1.0f - fx) * fy;
        float w10 = fx * (1.0f - fy),          w11 = fx * fy;
        f32x4 a = c00 * w00 + c01 * w01 + c10 * w10 + c11 * w11;
        const int sj = l >> 1, so = (l & 1) * 4;
        stage[sj][so + 0] = (__bf16)a.x;
        stage[sj][so + 1] = (__bf16)a.y;
        stage[sj][so + 2] = (__bf16)a.z;
        stage[sj][so + 3] = (__bf16)a.w;
    }

    __syncthreads();   // everyone done reading the landing zone (aliases feS)

    // ---- write feats tile, XOR-swizzled 16B chunks: chunk j -> j^(row&7) ----
    __bf16 (*feS)[64] = (__bf16 (*)[64])uSh;
    {
        const int sw = tid & 7;
        #pragma unroll
        for (int j = 0; j < 8; ++j)
            *(bf16x8*)&feS[tid][(j ^ sw) * 8] = stage[j];
    }

    __syncthreads();

    // ---- phase 2: per-wave [64x64] @ [64x64] MFMA ----
    const int lx = lane & 15, q = lane >> 4;
    const int asw = lx & 7;                 // row&7 for a-frag rows

    f32x4 acc[4][4];
    #pragma unroll
    for (int mt = 0; mt < 4; ++mt)
        #pragma unroll
        for (int nt = 0; nt < 4; ++nt)
            acc[mt][nt] = (f32x4)(0.0f);

    #pragma unroll
    for (int kc = 0; kc < 2; ++kc) {
        bf16x8 afr[4];
        #pragma unroll
        for (int mt = 0; mt < 4; ++mt)
            afr[mt] = *(const bf16x8*)&feS[wave * 64 + mt * 16 + lx][((kc * 4 + q) ^ asw) * 8];
        #pragma unroll
        for (int nt = 0; nt < 4; ++nt) {
            // one coalesced b128 from the pre-packed, L1-hot W0 fragment buffer
            bf16x8 bfr = *(const bf16x8*)(w0f + (size_t)(((kc * 4 + nt) * 4 + q) * 16 + lx) * 8);
            #pragma unroll
            for (int mt = 0; mt < 4; ++mt)
                acc[mt][nt] = __builtin_amdgcn_mfma_f32_16x16x32_bf16(
                    afr[mt], bfr, acc[mt][nt], 0, 0, 0);
        }
    }

    // ---- epilogue: softplus10 -> dot W1 -> reduce over 16 col-lanes ----
    float b0v[4], w1v[4];
    #pragma unroll
    for (int nt = 0; nt < 4; ++nt) {
        b0v[nt] = b0[nt * 16 + lx];     // 16-lane broadcast, L1-hot
        w1v[nt] = W1[nt * 16 + lx];
    }
    const float b1v = b1[0];
    const float d0 = (float)(1.0 / 192.0);
    const float d1 = (float)(2.0 / 191.0);

    #pragma unroll
    for (int mt = 0; mt < 4; ++mt) {
        float part[4];
        #pragma unroll
        for (int r = 0; r < 4; ++r) {
            float p = 0.0f;
            #pragma unroll
            for (int nt = 0; nt < 4; ++nt)
                p += softplus10(acc[mt][nt][r] + b0v[nt]) * w1v[nt];
            p += __shfl_xor(p, 1, 64);
            p += __shfl_xor(p, 2, 64);
            p += __shfl_xor(p, 4, 64);
            p += __shfl_xor(p, 8, 64);
            part[r] = p;
        }
        if (lx == 0) {
            const int g0 = blockIdx.x * BLOCK + wave * 64 + mt * 16 + q * 4;
            const int tt = g0 % T_SAMPLES;           // multiple of 4, no wrap in vec4
            f32x4 ov;
            ov.x = softplus10(part[0] + b1v) * (tt == 0 ? d0 : d1);
            ov.y = softplus10(part[1] + b1v) * d1;
            ov.z = softplus10(part[2] + b1v) * d1;
            ov.w = softplus10(part[3] + b1v) * d1;
            *(f32x4*)(out + g0) = ov;
        }
    }
}

extern "C" void kernel_launch(void* const* d_in, const int* in_sizes, int n_in,
                              void* d_out, int out_size, void* d_ws, size_t ws_size,
                              hipStream_t stream) {
    const float* x   = (const float*)d_in[0];
    const float* emb = (const float*)d_in[1];
    const float* W0  = (const float*)d_in[2];
    const float* b0  = (const float*)d_in[3];
    const float* W1  = (const float*)d_in[4];
    const float* b1  = (const float*)d_in[5];
    float* out = (float*)d_out;
    __bf16* w0f = (__bf16*)d_ws;          // 4096 bf16 = 8 KB fragment buffer

    // Replicate numpy's level constants with the same double-precision libm ops.
    LvlParams lp;
    const double bb = std::exp((std::log(2048.0) - std::log(2.0)) / 15.0);
    for (int l = 0; l < NUM_LEVELS; ++l) {
        double sc = 2.0 * std::pow(bb, (double)l) - 1.0;
        int rr = (int)std::ceil(sc) + 1;
        lp.s[l] = (float)sc;
        lp.res[l] = rr;
        lp.hashed[l] = ((long long)rr * (long long)rr > (long long)TABLE_SIZE) ? 1 : 0;
    }

    pack_w0<<<1, 256, 0, stream>>>(W0, w0f);

    const int nblk = (out_size + BLOCK - 1) / BLOCK;   // 1572864/256 = 6144
    nerf_fused<<<nblk, BLOCK, 0, stream>>>(x, emb, w0f, b0, W1, b1, out, lp);
}

// Round 5
// 371.251 us; speedup vs baseline: 2.0695x; 1.8496x over previous
//
#include <hip/hip_runtime.h>
#include <cmath>

#define NUM_LEVELS 16
#define TABLE_SIZE 524288
#define TMASK (TABLE_SIZE - 1)
#define HASH_PRIME 2654435761u
#define T_SAMPLES 192
#define BLOCK 256
#define PTS 64          // points per block; 4 waves split the 16 levels

typedef __bf16 bf16x8 __attribute__((ext_vector_type(8)));
typedef __bf16 bf16x4 __attribute__((ext_vector_type(4)));
typedef float f32x4 __attribute__((ext_vector_type(4)));

struct LvlParams {
    float s[NUM_LEVELS];
    int   res[NUM_LEVELS];
    int   hashed[NUM_LEVELS];
};

__device__ __forceinline__ float softplus10(float x) {
    float t = 10.0f * x;
    float e = __expf(-fabsf(t));
    return (fmaxf(t, 0.0f) + __logf(1.0f + e)) * 0.1f;
}

typedef __attribute__((address_space(1))) const void CGV;
typedef __attribute__((address_space(3))) void LDSV;

__device__ __forceinline__ void dma_gather16(const void* gaddr, void* lds_wave_base) {
    // per-lane global address; LDS dest = wave-uniform base + lane*16 (m104 semantics)
    __builtin_amdgcn_global_load_lds((CGV*)gaddr, (LDSV*)lds_wave_base, 16, 0, 0);
}

__device__ __forceinline__ void corner_idx(int cx, int cy, int res, int hashed,
                                           int& i00, int& i01, int& i10, int& i11) {
    if (hashed) {
        unsigned hy0 = (unsigned)cy * HASH_PRIME;
        unsigned hy1 = (unsigned)(cy + 1) * HASH_PRIME;
        i00 = (int)(((unsigned)cx ^ hy0) & TMASK);
        i01 = (int)(((unsigned)cx ^ hy1) & TMASK);
        i10 = (int)(((unsigned)(cx + 1) ^ hy0) & TMASK);
        i11 = (int)(((unsigned)(cx + 1) ^ hy1) & TMASK);
    } else {
        i00 = cy * res + cx; i10 = i00 + 1;
        i01 = i00 + res;     i11 = i01 + 1;
    }
}

__device__ __forceinline__ bf16x4 lerp4(f32x4 c00, f32x4 c01, f32x4 c10, f32x4 c11,
                                        float fx, float fy) {
    float w00 = (1.0f - fx) * (1.0f - fy), w01 = (1.0f - fx) * fy;
    float w10 = fx * (1.0f - fy),          w11 = fx * fy;
    f32x4 a = c00 * w00 + c01 * w01 + c10 * w10 + c11 * w11;
    bf16x4 r;
    r[0] = (__bf16)a.x; r[1] = (__bf16)a.y; r[2] = (__bf16)a.z; r[3] = (__bf16)a.w;
    return r;
}

// ---- prep: pack W0 into MFMA-B-fragment bf16 order + spread level params ----
// w0f flat f: j=f&7, lx=(f>>3)&15, q=(f>>7)&3, nt=(f>>9)&3, kc=f>>11
// k = kc*32+q*8+j ; n = nt*16+lx.
__global__ void prep(const float* __restrict__ W0, __bf16* __restrict__ w0f,
                     float* __restrict__ sArr, int* __restrict__ resArr,
                     int* __restrict__ hashArr, LvlParams lp) {
    const int t = threadIdx.x;
    if (t < NUM_LEVELS) {   // dynamic kernarg index -> scratch here; harmless
        sArr[t] = lp.s[t]; resArr[t] = lp.res[t]; hashArr[t] = lp.hashed[t];
    }
    #pragma unroll
    for (int i = 0; i < 16; ++i) {
        int f = t * 16 + i;
        int j = f & 7, lx = (f >> 3) & 15, q = (f >> 7) & 3, nt = (f >> 9) & 3, kc = f >> 11;
        int k = kc * 32 + q * 8 + j;
        int n = nt * 16 + lx;
        w0f[f] = (__bf16)W0[k * 64 + n];
    }
}

// acc is only 16 regs now (M=16 x N=64 per wave) -> (256,5) budget 102 total,
// ~86 arch: encode peak ~70 arch (4 levels/thread). No spill expected.
__launch_bounds__(BLOCK, 5)
__global__ void nerf_fused(const float* __restrict__ x,
                           const float* __restrict__ emb,
                           const __bf16* __restrict__ w0f,
                           const float* __restrict__ sArr,
                           const int* __restrict__ resArr,
                           const int* __restrict__ hashArr,
                           const float* __restrict__ b0,
                           const float* __restrict__ W1,
                           const float* __restrict__ b1,
                           float* __restrict__ out) {
    // Separate regions (no union, single barrier):
    //  land: 4 waves x 4 corners x 64 lanes x 16B = 16 KB  (DMA for level w+12)
    //  feS : 64 points x 72 bf16 (pad) = 9.2 KB
    __shared__ __align__(16) f32x4 land[16 * 64];
    __shared__ __align__(16) __bf16 feS[PTS][72];

    const int tid  = threadIdx.x;
    const int lane = tid & 63, w = tid >> 6;   // lane = point-in-block

    // ---- ray setup for point = lane (duplicated across 4 waves, L1-hot) ----
    const int gp  = blockIdx.x * PTS + lane;
    const int ray = gp / T_SAMPLES;
    const int t   = gp - ray * T_SAMPLES;

    const float2 o  = *(const float2*)(x + (size_t)ray * (T_SAMPLES * 2));
    const float2 ep = *(const float2*)(x + (size_t)ray * (T_SAMPLES * 2) + (T_SAMPLES - 1) * 2);
    float rdx = ep.x - o.x, rdy = ep.y - o.y;
    float inv = 1.0f / sqrtf(rdx * rdx + rdy * rdy);
    rdx *= inv; rdy *= inv;
    const float z = (float)((double)t * (2.0 / 191.0));
    float px = fminf(fmaxf(o.x + rdx * z, -1.0f), 1.0f);
    float py = fminf(fmaxf(o.y + rdy * z, -1.0f), 1.0f);
    const float ux = (px + 1.0f) * 0.5f;
    const float uy = (py + 1.0f) * 0.5f;

    // this wave's levels: w, w+4, w+8, w+12  (exactly one expensive level each)
    const int l0 = w, l1 = w + 4, l2 = w + 8, l3 = w + 12;

    // ---- level l3 (12..15): DMA gather, 4 corners, no VGPRs held ----
    float fx3, fy3;
    {
        float s = sArr[l3];
        float posx = ux * s + 0.5f, posy = uy * s + 0.5f;
        float pfx = floorf(posx), pfy = floorf(posy);
        fx3 = posx - pfx; fy3 = posy - pfy;
        int cx = (int)pfx, cy = (int)pfy;
        int i00, i01, i10, i11;
        corner_idx(cx, cy, resArr[l3], hashArr[l3], i00, i01, i10, i11);
        const f32x4* tb = (const f32x4*)(emb + (size_t)l3 * (TABLE_SIZE * 4));
        dma_gather16(tb + i00, land + (w * 4 + 0) * 64);
        dma_gather16(tb + i01, land + (w * 4 + 1) * 64);
        dma_gather16(tb + i10, land + (w * 4 + 2) * 64);
        dma_gather16(tb + i11, land + (w * 4 + 3) * 64);
    }

    // ---- level l2 (8..11): register loads (direct-indexed, L2-hot) ----
    f32x4 cre[4]; float fx2, fy2;
    {
        float s = sArr[l2];
        float posx = ux * s + 0.5f, posy = uy * s + 0.5f;
        float pfx = floorf(posx), pfy = floorf(posy);
        fx2 = posx - pfx; fy2 = posy - pfy;
        int cx = (int)pfx, cy = (int)pfy;
        int res = resArr[l2];
        int i00 = cy * res + cx, i10 = i00 + 1, i01 = i00 + res, i11 = i01 + 1;
        const f32x4* tb = (const f32x4*)(emb + (size_t)l2 * (TABLE_SIZE * 4));
        cre[0] = tb[i00]; cre[1] = tb[i01]; cre[2] = tb[i10]; cre[3] = tb[i11];
    }

    // ---- levels l1 (4..7) and l0 (0..3): tiny L1-resident tables ----
    f32x4 c1v[4]; float fx1, fy1;
    {
        float s = sArr[l1];
        float posx = ux * s + 0.5f, posy = uy * s + 0.5f;
        float pfx = floorf(posx), pfy = floorf(posy);
        fx1 = posx - pfx; fy1 = posy - pfy;
        int cx = (int)pfx, cy = (int)pfy;
        int res = resArr[l1];
        int i00 = cy * res + cx, i10 = i00 + 1, i01 = i00 + res, i11 = i01 + 1;
        const f32x4* tb = (const f32x4*)(emb + (size_t)l1 * (TABLE_SIZE * 4));
        c1v[0] = tb[i00]; c1v[1] = tb[i01]; c1v[2] = tb[i10]; c1v[3] = tb[i11];
    }
    f32x4 c0v[4]; float fx0, fy0;
    {
        float s = sArr[l0];
        float posx = ux * s + 0.5f, posy = uy * s + 0.5f;
        float pfx = floorf(posx), pfy = floorf(posy);
        fx0 = posx - pfx; fy0 = posy - pfy;
        int cx = (int)pfx, cy = (int)pfy;
        int res = resArr[l0];
        int i00 = cy * res + cx, i10 = i00 + 1, i01 = i00 + res, i11 = i01 + 1;
        const f32x4* tb = (const f32x4*)(emb + (size_t)l0 * (TABLE_SIZE * 4));
        c0v[0] = tb[i00]; c0v[1] = tb[i01]; c0v[2] = tb[i10]; c0v[3] = tb[i11];
    }

    // ---- consume small/mid levels straight into LDS feats (8B writes) ----
    *(bf16x4*)&feS[lane][l0 * 4] = lerp4(c0v[0], c0v[1], c0v[2], c0v[3], fx0, fy0);
    *(bf16x4*)&feS[lane][l1 * 4] = lerp4(c1v[0], c1v[1], c1v[2], c1v[3], fx1, fy1);
    *(bf16x4*)&feS[lane][l2 * 4] = lerp4(cre[0], cre[1], cre[2], cre[3], fx2, fy2);

    // ---- consume l3 from landing zone ----
    __builtin_amdgcn_s_waitcnt(0x0F70);   // vmcnt(0): this wave's DMAs landed
    {
        f32x4 c00 = land[(w * 4 + 0) * 64 + lane];
        f32x4 c01 = land[(w * 4 + 1) * 64 + lane];
        f32x4 c10 = land[(w * 4 + 2) * 64 + lane];
        f32x4 c11 = land[(w * 4 + 3) * 64 + lane];
        *(bf16x4*)&feS[lane][l3 * 4] = lerp4(c00, c01, c10, c11, fx3, fy3);
    }

    __syncthreads();   // all 4 waves' feature quarters visible

    // ---- MLP: wave w computes h for its own 16 points (M=16, N=64) ----
    const int lx = lane & 15, q = lane >> 4;

    f32x4 acc[4];
    #pragma unroll
    for (int nt = 0; nt < 4; ++nt) acc[nt] = (f32x4)(0.0f);

    #pragma unroll
    for (int kc = 0; kc < 2; ++kc) {
        bf16x8 afr = *(const bf16x8*)&feS[w * 16 + lx][kc * 32 + q * 8];
        #pragma unroll
        for (int nt = 0; nt < 4; ++nt) {
            bf16x8 bfr = *(const bf16x8*)(w0f + (size_t)(((kc * 4 + nt) * 4 + q) * 16 + lx) * 8);
            acc[nt] = __builtin_amdgcn_mfma_f32_16x16x32_bf16(afr, bfr, acc[nt], 0, 0, 0);
        }
    }

    // ---- epilogue: softplus10 -> dot W1 -> reduce over 16 col-lanes ----
    float b0v[4], w1v[4];
    #pragma unroll
    for (int nt = 0; nt < 4; ++nt) {
        b0v[nt] = b0[nt * 16 + lx];
        w1v[nt] = W1[nt * 16 + lx];
    }
    const float b1v = b1[0];
    const float d0 = (float)(1.0 / 192.0);
    const float d1 = (float)(2.0 / 191.0);

    float part[4];
    #pragma unroll
    for (int r = 0; r < 4; ++r) {
        float p = 0.0f;
        #pragma unroll
        for (int nt = 0; nt < 4; ++nt)
            p += softplus10(acc[nt][r] + b0v[nt]) * w1v[nt];
        p += __shfl_xor(p, 1, 64);
        p += __shfl_xor(p, 2, 64);
        p += __shfl_xor(p, 4, 64);
        p += __shfl_xor(p, 8, 64);
        part[r] = p;
    }
    if (lx == 0) {
        const int g0 = blockIdx.x * PTS + w * 16 + q * 4;   // multiple of 4
        const int tt = g0 % T_SAMPLES;
        f32x4 ov;
        ov.x = softplus10(part[0] + b1v) * (tt == 0 ? d0 : d1);
        ov.y = softplus10(part[1] + b1v) * d1;
        ov.z = softplus10(part[2] + b1v) * d1;
        ov.w = softplus10(part[3] + b1v) * d1;
        *(f32x4*)(out + g0) = ov;
    }
}

extern "C" void kernel_launch(void* const* d_in, const int* in_sizes, int n_in,
                              void* d_out, int out_size, void* d_ws, size_t ws_size,
                              hipStream_t stream) {
    const float* x   = (const float*)d_in[0];
    const float* emb = (const float*)d_in[1];
    const float* W0  = (const float*)d_in[2];
    const float* b0  = (const float*)d_in[3];
    const float* W1  = (const float*)d_in[4];
    const float* b1  = (const float*)d_in[5];
    float* out = (float*)d_out;

    // d_ws layout: [0,8192) w0f bf16; [8192,8256) sArr; [8256,8320) resArr;
    // [8320,8384) hashArr
    char* ws = (char*)d_ws;
    __bf16* w0f   = (__bf16*)ws;
    float* sArr   = (float*)(ws + 8192);
    int*   resArr = (int*)(ws + 8256);
    int*   hashArr= (int*)(ws + 8320);

    // Replicate numpy's level constants with the same host libm double ops.
    LvlParams lp;
    const double bb = std::exp((std::log(2048.0) - std::log(2.0)) / 15.0);
    for (int l = 0; l < NUM_LEVELS; ++l) {
        double sc = 2.0 * std::pow(bb, (double)l) - 1.0;
        int rr = (int)std::ceil(sc) + 1;
        lp.s[l] = (float)sc;
        lp.res[l] = rr;
        lp.hashed[l] = ((long long)rr * (long long)rr > (long long)TABLE_SIZE) ? 1 : 0;
    }

    prep<<<1, 256, 0, stream>>>(W0, w0f, sArr, resArr, hashArr, lp);

    const int nblk = out_size / PTS;   // 1572864/64 = 24576
    nerf_fused<<<nblk, BLOCK, 0, stream>>>(x, emb, w0f, sArr, resArr, hashArr,
                                           b0, W1, b1, out);
}